// Round 19
// baseline (93.590 us; speedup 1.0000x reference)
//
#include <hip/hip_runtime.h>

typedef float fx4 __attribute__((ext_vector_type(4)));
typedef short s16x8 __attribute__((ext_vector_type(8)));
typedef __bf16 bfx8 __attribute__((ext_vector_type(8)));

#define KN 1024
#define TT 16384
#define NOUT 16382
#define NKT 32      // 32 tiles; tile = {s=0,s=1} x 32 m-rows = 64 k'
#define COLP 16640  // padded X^T cols (65 x 256)
#define HLDS 32832  // per-buffer LDS: A 16384 + B 16384 + seam 64

// ws: Xbf (34,078,720 B) at 0; Wc (4 MiB) after
#define APK_OFF 34078720u

__device__ __forceinline__ unsigned short f2bf(float f) {
  return __builtin_bit_cast(unsigned short, (__bf16)f);
}

__device__ __forceinline__ void gll16(const void* g, void* l) {
  __builtin_amdgcn_global_load_lds(
      (const __attribute__((address_space(1))) void*)g,
      (__attribute__((address_space(3))) void*)l, 16, 0, 0);
}

// ---- kernel 1 (fused): blocks 0-1023 weights (inline masks); 1024+ pack X^T ----
// Wc u16 idx = mb*524288 + t*16384 + s*8192 + kb*2048 + rloc*8 + ii
// Xbf unit (o,c): 16 B = 8 bf16 = X[o*8+i, c] (0 for c >= 16384)
__global__ __launch_bounds__(256) void k_wp(const float* __restrict__ A,
                                            const float* __restrict__ alpha,
                                            const float* __restrict__ beta0,
                                            const float* __restrict__ beta1,
                                            const float* __restrict__ X,
                                            unsigned short* __restrict__ Wc,
                                            unsigned short* __restrict__ Xbf) {
  int tid = threadIdx.x;
  if (blockIdx.x >= 1024) {
    // ---------------- pack path: plain bf16 X^T, octet-major ----------------
    int p = blockIdx.x - 1024;       // 0..8319
    int o = p & 127;                 // m-octet
    int cb = p >> 7;                 // 0..64
    int c = cb * 256 + tid;          // 0..16639
    unsigned v[4];
#pragma unroll
    for (int q = 0; q < 4; ++q) {
      float f0 = 0.f, f1 = 0.f;
      if (c < TT) {
        f0 = X[(size_t)(o * 8 + q * 2) * TT + c];
        f1 = X[(size_t)(o * 8 + q * 2 + 1) * TT + c];
      }
      v[q] = (unsigned)f2bf(f0) | ((unsigned)f2bf(f1) << 16);
    }
    uint4 w; w.x = v[0]; w.y = v[1]; w.z = v[2]; w.w = v[3];
    *reinterpret_cast<uint4*>(Xbf + ((size_t)o * COLP + c) * 8) = w;
    return;
  }
  // ---------------- weights path (masks computed inline from A) ----------------
  __shared__ unsigned reach[32];
  __shared__ unsigned ex2[32];
  __shared__ unsigned short list[1056];
  __shared__ int nl;
  int k = blockIdx.x;
  int lane = tid & 63, wv = tid >> 6;
  if (tid == 0) nl = 0;
  if (tid < 32) ex2[tid] = 0;
  // build reach = N(k) via ballot over A row k
  for (int i = 0; i < 4; ++i) {
    int n = i * 256 + tid;
    bool bit = (A[(size_t)k * KN + n] > 0.5f) && (n != k);
    unsigned long long m = __ballot(bit);
    if (lane == 0) {
      reach[i * 8 + wv * 2]     = (unsigned)m;
      reach[i * 8 + wv * 2 + 1] = (unsigned)(m >> 32);
    }
  }
  __syncthreads();
  if (tid == 0) reach[k >> 5] |= 1u << (k & 31);   // add self
  __syncthreads();
  for (int m = tid; m < KN; m += 256)
    if ((reach[m >> 5] >> (m & 31)) & 1) {
      int i = atomicAdd(&nl, 1);
      list[i] = (unsigned short)m;
    }
  __syncthreads();
  int n2 = nl;
  // ex2 = union of N(m) for m in reach (read A rows directly; L2/L3-resident)
  for (int i = 0; i < n2; ++i) {
    int m = list[i];
    for (int i2 = 0; i2 < 4; ++i2) {
      int n = i2 * 256 + tid;
      bool bit = A[(size_t)m * KN + n] > 0.5f;     // diag(A)=0
      unsigned long long bm = __ballot(bit);
      if (lane == 0) {
        atomicOr(&ex2[i2 * 8 + wv * 2], (unsigned)bm);
        atomicOr(&ex2[i2 * 8 + wv * 2 + 1], (unsigned)(bm >> 32));
      }
    }
  }
  __syncthreads();
  if (tid < 32) ex2[tid] &= ~reach[tid];          // distance exactly 2
  __syncthreads();
  int d1 = 0, d2 = 0;
  for (int w = 0; w < 32; ++w) { d1 += __popc(reach[w]); d2 += __popc(ex2[w]); }
  d1 -= 1;
  float rd1 = 1.0f / fmaxf((float)d1, 1.0f);
  float rd2 = 1.0f / fmaxf((float)d2, 1.0f);
  float c00 = beta0[0] * rd1, c01 = beta0[1] * rd1;
  float c10 = beta1[0] * rd2, c11 = beta1[1] * rd2;
  float a0 = alpha[0], a1 = alpha[1];
  int mb = k >> 8, rloc = k & 255;
  for (int q = 0; q < 4; ++q) {
    int n = tid * 4 + q;
    bool in1 = (((reach[n >> 5] >> (n & 31)) & 1) != 0) && (n != k);
    bool in2 = ((ex2[n >> 5] >> (n & 31)) & 1) != 0;
    float v0 = (in1 ? c00 : 0.f) + (in2 ? c10 : 0.f) + (n == k ? a0 : 0.f);
    float v1 = (in1 ? c01 : 0.f) + (in2 ? c11 : 0.f) + (n == k ? a1 : 0.f);
    int t = n >> 5, kb2 = (n >> 3) & 3, ii = n & 7;
    size_t base = (size_t)mb * 524288 + (size_t)t * 16384 +
                  kb2 * 2048 + rloc * 8 + ii;
    Wc[base] = f2bf(v0);            // s = 0 (pairs with X[., j+1])
    Wc[base + 8192] = f2bf(v1);     // s = 1 (pairs with X[., j])
  }
}

// ---- kernel 2: 128x256-tile GEMM, 2 blocks/CU (R16 verbatim, best known) ----
// 256 thr, 4 waves (2M x 2N), wave tile 64x128. B staged once/tile (s-shared);
// s=0 reads cols+1 (seam at c==256), s=1 cols. One vmcnt(0)+barrier per tile;
// reads from buf kt&1, stages into buf (kt+1)&1.
__global__ __launch_bounds__(256, 2) void k_gemm(const char* __restrict__ Apk,
                                                 const char* __restrict__ Xbf,
                                                 float* __restrict__ Y) {
  __shared__ __align__(16) char lds[2 * HLDS];
  int bid = blockIdx.x;
  int swz = (bid & 7) * 64 + (bid >> 3);   // XCD-contiguous (512 % 8 == 0)
  int jb = swz >> 3, mb = swz & 7;         // jb 0..63, mb 0..7 (128-row slices)
  int mb4 = mb >> 1, half = mb & 1;
  int tid = threadIdx.x;
  int lane = tid & 63, wv = tid >> 6;
  int wm = wv >> 1, wn = wv & 1;           // wave tile: rows wm*64, cols wn*128
  int kb = lane >> 4, ml = lane & 15;
  const char* Asrc = Apk + (size_t)mb4 * 1048576;  // byte base of mb4 slice

  fx4 acc[4][8];
#pragma unroll
  for (int a = 0; a < 4; ++a)
#pragma unroll
    for (int b = 0; b < 8; ++b) acc[a][b] = (fx4){0.f, 0.f, 0.f, 0.f};

  auto stageA = [&](int t) {   // 16 KB (both s halves of this block's 128 rows)
    char* dst = lds + (t & 1) * HLDS;
    int ts = t & (NKT - 1);
#pragma unroll
    for (int q = 0; q < 4; ++q) {
      int u = tid + q * 256;
      int s_ = u >> 9, kb_ = (u >> 7) & 3, r_ = u & 127;
      const char* src = Asrc + (size_t)ts * 32768 + s_ * 16384 + kb_ * 4096 +
                        (half * 128 + r_) * 16;
      gll16(src, dst + u * 16);
    }
  };
  auto stageB = [&](int t) {   // 16 KB main + seam
    char* dstB = lds + (t & 1) * HLDS + 16384;
    int ts = t & (NKT - 1);
#pragma unroll
    for (int u2 = 0; u2 < 4; ++u2) {
      int u = tid + u2 * 256;
      const char* src = Xbf +
          ((size_t)(ts * 4 + (u >> 8)) * COLP + jb * 256 + (u & 255)) * 16;
      gll16(src, dstB + u * 16);
    }
    if (tid < 4) {   // seam col 256; lanes 0-3 land at dst+lane*16
      const char* src = Xbf +
          ((size_t)(ts * 4 + tid) * COLP + jb * 256 + 256) * 16;
      gll16(src, dstB + 16384);
    }
  };

#define READ_A(dst, t, s)                                                           \
  do {                                                                              \
    const char* Ah_ = lds + ((t) & 1) * HLDS + (s) * 8192;                          \
    _Pragma("unroll") for (int mf = 0; mf < 4; ++mf)                                \
      dst[mf] = *(const s16x8*)(Ah_ +                                               \
          (size_t)(kb * 128 + wm * 64 + mf * 16 + ml) * 16);                        \
  } while (0)
#define READ_B(dst, t, off)                                                         \
  do {                                                                              \
    const char* Bh_ = lds + ((t) & 1) * HLDS + 16384;                               \
    _Pragma("unroll") for (int nf = 0; nf < 8; ++nf) {                              \
      int c_ = wn * 128 + nf * 16 + ml + (off);                                     \
      const char* a_ = Bh_ + (size_t)(kb * 256 + c_) * 16;                          \
      if ((off) == 1 && nf == 7) {                                                  \
        if (c_ == 256) a_ = Bh_ + 16384 + kb * 16;                                  \
      }                                                                             \
      dst[nf] = *(const s16x8*)a_;                                                  \
    }                                                                               \
  } while (0)
#define MFMA32(a_, b_)                                                              \
  do {                                                                              \
    __builtin_amdgcn_s_setprio(1);                                                  \
    _Pragma("unroll") for (int mf = 0; mf < 4; ++mf)                                \
      _Pragma("unroll") for (int nf = 0; nf < 8; ++nf)                              \
        acc[mf][nf] = __builtin_amdgcn_mfma_f32_16x16x32_bf16(                      \
            __builtin_bit_cast(bfx8, a_[mf]), __builtin_bit_cast(bfx8, b_[nf]),     \
            acc[mf][nf], 0, 0, 0);                                                  \
    __builtin_amdgcn_s_setprio(0);                                                  \
  } while (0)

  s16x8 aA[4], bA[8];

  // prologue: stage tile 0; full drain; barrier
  stageA(0); stageB(0);
  asm volatile("s_waitcnt vmcnt(0)" ::: "memory");
  __builtin_amdgcn_s_barrier();

  for (int kt = 0; kt < NKT; ++kt) {
    bool st = (kt + 1) < NKT;   // skip useless wrap-stage on last tile
    // s=0 pass (B at cols+1); stage A(kt+1) early
    READ_B(bA, kt, 1);
    READ_A(aA, kt, 0);
    if (st) stageA(kt + 1);
    MFMA32(aA, bA);
    // s=1 pass (B at cols); stage B(kt+1)
    READ_B(bA, kt, 0);
    READ_A(aA, kt, 1);
    if (st) stageB(kt + 1);
    MFMA32(aA, bA);
    asm volatile("s_waitcnt vmcnt(0)" ::: "memory");
    __builtin_amdgcn_s_barrier();
  }

  // epilogue: C/D layout col=lane&15, row=(lane>>4)*4+r
  int c0 = jb * 256 + wn * 128;
  int r0 = mb * 128 + wm * 64;
#pragma unroll
  for (int mf = 0; mf < 4; ++mf)
#pragma unroll
    for (int nf = 0; nf < 8; ++nf) {
      int c = c0 + nf * 16 + ml;
      if (c < NOUT) {
        int r = r0 + mf * 16 + (lane >> 4) * 4;
#pragma unroll
        for (int i = 0; i < 4; ++i)
          Y[(size_t)(r + i) * NOUT + c] = acc[mf][nf][i];
      }
    }
#undef READ_A
#undef READ_B
#undef MFMA32
}

extern "C" void kernel_launch(void* const* d_in, const int* in_sizes, int n_in,
                              void* d_out, int out_size, void* d_ws, size_t ws_size,
                              hipStream_t stream) {
  const float* X     = (const float*)d_in[0];
  const float* A     = (const float*)d_in[1];
  const float* alpha = (const float*)d_in[2];
  const float* beta0 = (const float*)d_in[3];
  const float* beta1 = (const float*)d_in[4];
  float* Y = (float*)d_out;
  char* ws = (char*)d_ws;
  char* Xbf = ws;                       // 34,078,720 B
  char* Wc  = ws + APK_OFF;             // 4 MiB

  k_wp<<<dim3(9344), dim3(256), 0, stream>>>(A, alpha, beta0, beta1, X,
                                             (unsigned short*)Wc,
                                             (unsigned short*)Xbf);
  k_gemm<<<dim3(512), dim3(256), 0, stream>>>(Wc, Xbf, Y);
}

// Round 20
// 81.931 us; speedup vs baseline: 1.1423x; 1.1423x over previous
//
#include <hip/hip_runtime.h>

typedef float fx4 __attribute__((ext_vector_type(4)));
typedef short s16x8 __attribute__((ext_vector_type(8)));
typedef __bf16 bfx8 __attribute__((ext_vector_type(8)));

#define KN 1024
#define TT 16384
#define NOUT 16382
#define NKT 32      // 32 tiles; tile = {s=0,s=1} x 32 m-rows = 64 k'
#define COLP 16640  // padded X^T cols (65 x 256)
#define HLDS 32832  // per-buffer LDS: A 16384 + B 16384 + seam 64

// ws: Xbf (34,078,720 B) at 0; Apk (4 MiB); B1 bitmasks
#define APK_OFF 34078720u
#define B1_OFF  (APK_OFF + 4194304u)

__device__ __forceinline__ unsigned short f2bf(float f) {
  return __builtin_bit_cast(unsigned short, (__bf16)f);
}

__device__ __forceinline__ void gll16(const void* g, void* l) {
  __builtin_amdgcn_global_load_lds(
      (const __attribute__((address_space(1))) void*)g,
      (__attribute__((address_space(3))) void*)l, 16, 0, 0);
}

// ---- kernel 1: adjacency bitmask rows ----
__global__ __launch_bounds__(256) void k_masks(const float* __restrict__ A,
                                               unsigned* __restrict__ B1) {
  int k = blockIdx.x;
  int tid = threadIdx.x;
  int wv = tid >> 6, lane = tid & 63;
  for (int i = 0; i < 4; ++i) {
    int n = i * 256 + wv * 64 + lane;
    bool bit = (A[(size_t)k * KN + n] > 0.5f) && (n != k);
    unsigned long long m = __ballot(bit);
    if (lane == 0) {
      B1[k * 32 + i * 8 + wv * 2]     = (unsigned)m;
      B1[k * 32 + i * 8 + wv * 2 + 1] = (unsigned)(m >> 32);
    }
  }
}

// ---- kernel 2 (fused): blocks 0-1023 build Wc (s-stacked); 1024+ pack X^T ----
// Wc u16 idx = mb*524288 + t*16384 + s*8192 + kb*2048 + rloc*8 + ii  (mb 0..3, rloc 0..255)
// Xbf unit (o,c): 16 B = 8 bf16 = X[o*8+i, c] (0 for c >= 16384)
__global__ __launch_bounds__(256) void k_wp(const unsigned* __restrict__ B1,
                                            const float* __restrict__ alpha,
                                            const float* __restrict__ beta0,
                                            const float* __restrict__ beta1,
                                            const float* __restrict__ X,
                                            unsigned short* __restrict__ Wc,
                                            unsigned short* __restrict__ Xbf) {
  int tid = threadIdx.x;
  if (blockIdx.x >= 1024) {
    // ---------------- pack path: plain bf16 X^T, octet-major ----------------
    int p = blockIdx.x - 1024;       // 0..8319
    int o = p & 127;                 // m-octet
    int cb = p >> 7;                 // 0..64
    int c = cb * 256 + tid;          // 0..16639
    unsigned v[4];
#pragma unroll
    for (int q = 0; q < 4; ++q) {
      float f0 = 0.f, f1 = 0.f;
      if (c < TT) {
        f0 = X[(size_t)(o * 8 + q * 2) * TT + c];
        f1 = X[(size_t)(o * 8 + q * 2 + 1) * TT + c];
      }
      v[q] = (unsigned)f2bf(f0) | ((unsigned)f2bf(f1) << 16);
    }
    uint4 w; w.x = v[0]; w.y = v[1]; w.z = v[2]; w.w = v[3];
    *reinterpret_cast<uint4*>(Xbf + ((size_t)o * COLP + c) * 8) = w;
    return;
  }
  // ---------------- weights path ----------------
  __shared__ unsigned reach[32];
  __shared__ unsigned ex2[32];
  __shared__ unsigned short list[1056];
  __shared__ int nl;
  int k = blockIdx.x;
  if (tid == 0) nl = 0;
  if (tid < 32) {
    unsigned r = B1[k * 32 + tid];
    if (tid == (k >> 5)) r |= 1u << (k & 31);  // reach = {k} | N(k)
    reach[tid] = r;
    ex2[tid] = 0;
  }
  __syncthreads();
  for (int m = tid; m < KN; m += 256)
    if ((reach[m >> 5] >> (m & 31)) & 1) {
      int i = atomicAdd(&nl, 1);
      list[i] = (unsigned short)m;
    }
  __syncthreads();
  int n2 = nl;
  for (int i = 0; i < n2; ++i) {
    int m = list[i];
    if (tid < 32) ex2[tid] |= B1[m * 32 + tid];
  }
  __syncthreads();
  if (tid < 32) ex2[tid] &= ~reach[tid];          // distance exactly 2
  __syncthreads();
  int d1 = 0, d2 = 0;
  for (int w = 0; w < 32; ++w) { d1 += __popc(reach[w]); d2 += __popc(ex2[w]); }
  d1 -= 1;
  float rd1 = 1.0f / fmaxf((float)d1, 1.0f);
  float rd2 = 1.0f / fmaxf((float)d2, 1.0f);
  float c00 = beta0[0] * rd1, c01 = beta0[1] * rd1;
  float c10 = beta1[0] * rd2, c11 = beta1[1] * rd2;
  float a0 = alpha[0], a1 = alpha[1];
  int mb = k >> 8, rloc = k & 255;
  for (int q = 0; q < 4; ++q) {
    int n = tid * 4 + q;
    bool in1 = (((reach[n >> 5] >> (n & 31)) & 1) != 0) && (n != k);
    bool in2 = ((ex2[n >> 5] >> (n & 31)) & 1) != 0;
    float v0 = (in1 ? c00 : 0.f) + (in2 ? c10 : 0.f) + (n == k ? a0 : 0.f);
    float v1 = (in1 ? c01 : 0.f) + (in2 ? c11 : 0.f) + (n == k ? a1 : 0.f);
    int t = n >> 5, kb2 = (n >> 3) & 3, ii = n & 7;
    size_t base = (size_t)mb * 524288 + (size_t)t * 16384 +
                  kb2 * 2048 + rloc * 8 + ii;
    Wc[base] = f2bf(v0);            // s = 0 (pairs with X[., j+1])
    Wc[base + 8192] = f2bf(v1);     // s = 1 (pairs with X[., j])
  }
}

// ---- kernel 3: 128x256-tile GEMM, 2 blocks/CU (independent barrier domains) ----
// 256 thr, 4 waves (2M x 2N), wave tile 64x128. B staged once/tile (s-shared);
// s=0 reads cols+1 (seam at c==256), s=1 cols. One vmcnt(0)+barrier per tile;
// reads from buf kt&1, stages into buf (kt+1)&1.
__global__ __launch_bounds__(256, 2) void k_gemm(const char* __restrict__ Apk,
                                                 const char* __restrict__ Xbf,
                                                 float* __restrict__ Y) {
  __shared__ __align__(16) char lds[2 * HLDS];
  int bid = blockIdx.x;
  int swz = (bid & 7) * 64 + (bid >> 3);   // XCD-contiguous (512 % 8 == 0)
  int jb = swz >> 3, mb = swz & 7;         // jb 0..63, mb 0..7 (128-row slices)
  int mb4 = mb >> 1, half = mb & 1;
  int tid = threadIdx.x;
  int lane = tid & 63, wv = tid >> 6;
  int wm = wv >> 1, wn = wv & 1;           // wave tile: rows wm*64, cols wn*128
  int kb = lane >> 4, ml = lane & 15;
  const char* Asrc = Apk + (size_t)mb4 * 1048576;  // byte base of mb4 slice

  fx4 acc[4][8];
#pragma unroll
  for (int a = 0; a < 4; ++a)
#pragma unroll
    for (int b = 0; b < 8; ++b) acc[a][b] = (fx4){0.f, 0.f, 0.f, 0.f};

  auto stageA = [&](int t) {   // 16 KB (both s halves of this block's 128 rows)
    char* dst = lds + (t & 1) * HLDS;
    int ts = t & (NKT - 1);
#pragma unroll
    for (int q = 0; q < 4; ++q) {
      int u = tid + q * 256;
      int s_ = u >> 9, kb_ = (u >> 7) & 3, r_ = u & 127;
      const char* src = Asrc + (size_t)ts * 32768 + s_ * 16384 + kb_ * 4096 +
                        (half * 128 + r_) * 16;
      gll16(src, dst + u * 16);
    }
  };
  auto stageB = [&](int t) {   // 16 KB main + seam
    char* dstB = lds + (t & 1) * HLDS + 16384;
    int ts = t & (NKT - 1);
#pragma unroll
    for (int u2 = 0; u2 < 4; ++u2) {
      int u = tid + u2 * 256;
      const char* src = Xbf +
          ((size_t)(ts * 4 + (u >> 8)) * COLP + jb * 256 + (u & 255)) * 16;
      gll16(src, dstB + u * 16);
    }
    if (tid < 4) {   // seam col 256; lanes 0-3 land at dst+lane*16
      const char* src = Xbf +
          ((size_t)(ts * 4 + tid) * COLP + jb * 256 + 256) * 16;
      gll16(src, dstB + 16384);
    }
  };

#define READ_A(dst, t, s)                                                           \
  do {                                                                              \
    const char* Ah_ = lds + ((t) & 1) * HLDS + (s) * 8192;                          \
    _Pragma("unroll") for (int mf = 0; mf < 4; ++mf)                                \
      dst[mf] = *(const s16x8*)(Ah_ +                                               \
          (size_t)(kb * 128 + wm * 64 + mf * 16 + ml) * 16);                        \
  } while (0)
#define READ_B(dst, t, off)                                                         \
  do {                                                                              \
    const char* Bh_ = lds + ((t) & 1) * HLDS + 16384;                               \
    _Pragma("unroll") for (int nf = 0; nf < 8; ++nf) {                              \
      int c_ = wn * 128 + nf * 16 + ml + (off);                                     \
      const char* a_ = Bh_ + (size_t)(kb * 256 + c_) * 16;                          \
      if ((off) == 1 && nf == 7) {                                                  \
        if (c_ == 256) a_ = Bh_ + 16384 + kb * 16;                                  \
      }                                                                             \
      dst[nf] = *(const s16x8*)a_;                                                  \
    }                                                                               \
  } while (0)
#define MFMA32(a_, b_)                                                              \
  do {                                                                              \
    __builtin_amdgcn_s_setprio(1);                                                  \
    _Pragma("unroll") for (int mf = 0; mf < 4; ++mf)                                \
      _Pragma("unroll") for (int nf = 0; nf < 8; ++nf)                              \
        acc[mf][nf] = __builtin_amdgcn_mfma_f32_16x16x32_bf16(                      \
            __builtin_bit_cast(bfx8, a_[mf]), __builtin_bit_cast(bfx8, b_[nf]),     \
            acc[mf][nf], 0, 0, 0);                                                  \
    __builtin_amdgcn_s_setprio(0);                                                  \
  } while (0)

  s16x8 aA[4], bA[8];

  // prologue: stage tile 0; full drain; barrier
  stageA(0); stageB(0);
  asm volatile("s_waitcnt vmcnt(0)" ::: "memory");
  __builtin_amdgcn_s_barrier();

  for (int kt = 0; kt < NKT; ++kt) {
    bool st = (kt + 1) < NKT;   // skip useless wrap-stage on last tile
    // s=0 pass (B at cols+1); stage A(kt+1) early
    READ_B(bA, kt, 1);
    READ_A(aA, kt, 0);
    if (st) stageA(kt + 1);
    MFMA32(aA, bA);
    // s=1 pass (B at cols); stage B(kt+1)
    READ_B(bA, kt, 0);
    READ_A(aA, kt, 1);
    if (st) stageB(kt + 1);
    MFMA32(aA, bA);
    asm volatile("s_waitcnt vmcnt(0)" ::: "memory");
    __builtin_amdgcn_s_barrier();
  }

  // epilogue: C/D layout col=lane&15, row=(lane>>4)*4+r
  int c0 = jb * 256 + wn * 128;
  int r0 = mb * 128 + wm * 64;
#pragma unroll
  for (int mf = 0; mf < 4; ++mf)
#pragma unroll
    for (int nf = 0; nf < 8; ++nf) {
      int c = c0 + nf * 16 + ml;
      if (c < NOUT) {
        int r = r0 + mf * 16 + (lane >> 4) * 4;
#pragma unroll
        for (int i = 0; i < 4; ++i)
          Y[(size_t)(r + i) * NOUT + c] = acc[mf][nf][i];
      }
    }
#undef READ_A
#undef READ_B
#undef MFMA32
}

extern "C" void kernel_launch(void* const* d_in, const int* in_sizes, int n_in,
                              void* d_out, int out_size, void* d_ws, size_t ws_size,
                              hipStream_t stream) {
  const float* X     = (const float*)d_in[0];
  const float* A     = (const float*)d_in[1];
  const float* alpha = (const float*)d_in[2];
  const float* beta0 = (const float*)d_in[3];
  const float* beta1 = (const float*)d_in[4];
  float* Y = (float*)d_out;
  char* ws = (char*)d_ws;
  char* Xbf = ws;                       // 34,078,720 B
  char* Apk = ws + APK_OFF;             // 4 MiB
  unsigned* B1 = (unsigned*)(ws + B1_OFF);

  k_masks<<<dim3(1024), dim3(256), 0, stream>>>(A, B1);
  k_wp<<<dim3(9344), dim3(256), 0, stream>>>(B1, alpha, beta0, beta1, X,
                                             (unsigned short*)Apk,
                                             (unsigned short*)Xbf);
  k_gemm<<<dim3(512), dim3(256), 0, stream>>>(Apk, Xbf, Y);
}